// Round 13
// baseline (166.756 us; speedup 1.0000x reference)
//
#include <hip/hip_runtime.h>
#include <cmath>

// Problem constants: B=32768, N=17, D=2, K=3, H=64
#define NBATCH 32768
#define NJOINT 17
#define OUT0_ELEMS (NBATCH * NJOINT * 15)          // out[B,N,3,5]
#define KJS_OFF    OUT0_ELEMS                      // k_js[B,N]
#define MASK_OFF   (KJS_OFF + NBATCH * NJOINT)     // mask[B,N,3]

#define WN_STRIDE 774
#define WS_DOUBLES (NJOINT * WN_STRIDE)

// 255 blocks = 17 n x 15 b-chunks; chunk size ceil(32768/15) = 2185.
#define NCHUNK 15
#define CHUNKB 2185

__device__ __forceinline__ float sel3f(int i, float a, float b, float c) {
    return (i == 0) ? a : ((i == 1) ? b : c);
}

// --------------------------------------------------------------------------
// Prelude: fp64 copies of k/w weights (escape path only).
// --------------------------------------------------------------------------
__global__ void cvt_weights_f64(
    const float* __restrict__ kW1, const float* __restrict__ kb1,
    const float* __restrict__ kW2, const float* __restrict__ kb2,
    const float* __restrict__ wW1, const float* __restrict__ wb1,
    const float* __restrict__ wW2, const float* __restrict__ wb2,
    double* __restrict__ dws)
{
    const int n = blockIdx.x;
    double* o = dws + (size_t)n * WN_STRIDE;
    for (int i = threadIdx.x; i < WN_STRIDE; i += blockDim.x) {
        int j = i;
        const float* W1 = kW1; const float* b1 = kb1;
        const float* W2 = kW2; const float* b2 = kb2;
        if (j >= 387) { j -= 387; W1 = wW1; b1 = wb1; W2 = wW2; b2 = wb2; }
        float v;
        if (j < 128)      v = W1[n * 128 + j];
        else if (j < 192) v = b1[n * 64 + (j - 128)];
        else if (j < 384) v = W2[n * 192 + (j - 192)];
        else              v = b2[n * 3 + (j - 384)];
        o[i] = (double)v;
    }
}

// --------------------------------------------------------------------------
// fp32 MLP (2 -> 64 -> 3), one point. Per-point fma sequence identical to
// the r9 passing kernel (mlp32_2's per-point chain).
// --------------------------------------------------------------------------
__device__ __forceinline__ void mlp32_1(
    const float* __restrict__ W1, const float* __restrict__ b1f,
    const float* __restrict__ W2f, const float* __restrict__ b2f, int n,
    float x0, float x1, float& l0, float& l1, float& l2)
{
    const float* W1a = W1 + n * 128;
    const float* W1b = W1a + 64;
    const float* b1  = b1f + n * 64;
    const float* W2  = W2f + n * 192;
    l0 = b2f[n * 3 + 0];
    l1 = b2f[n * 3 + 1];
    l2 = b2f[n * 3 + 2];
    #pragma unroll 4
    for (int h = 0; h < 64; ++h) {
        const float wa = W1a[h], wb = W1b[h], bb = b1[h];
        const float w0 = W2[h * 3 + 0], w1 = W2[h * 3 + 1], w2 = W2[h * 3 + 2];
        float hv = fmaxf(fmaf(x1, wb, fmaf(x0, wa, bb)), 0.0f);
        l0 = fmaf(hv, w0, l0);
        l1 = fmaf(hv, w1, l1);
        l2 = fmaf(hv, w2, l2);
    }
}

// --------------------------------------------------------------------------
// fp64 escape: EXACT sequence of the proven passing kernels.
// --------------------------------------------------------------------------
__device__ __forceinline__ void mlp64_ws_1(
    const double* __restrict__ gws, double x0, double x1,
    double& l0, double& l1, double& l2)
{
    const double* W1a = gws;
    const double* W1b = gws + 64;
    const double* b1  = gws + 128;
    const double* W2  = gws + 192;
    l0 = gws[384]; l1 = gws[385]; l2 = gws[386];
    #pragma unroll 4
    for (int h = 0; h < 64; ++h) {
        double hv = fmax(fma(x1, W1b[h], fma(x0, W1a[h], b1[h])), 0.0);
        l0 = fma(hv, W2[h * 3 + 0], l0);
        l1 = fma(hv, W2[h * 3 + 1], l1);
        l2 = fma(hv, W2[h * 3 + 2], l2);
    }
}

__device__ __forceinline__ void mlp64_cvt_1(
    const float* __restrict__ W1, const float* __restrict__ b1f,
    const float* __restrict__ W2f, const float* __restrict__ b2f, int n,
    double x0, double x1, double& l0, double& l1, double& l2)
{
    const float* W1a = W1 + n * 128;
    const float* W1b = W1a + 64;
    const float* b1  = b1f + n * 64;
    const float* W2  = W2f + n * 192;
    l0 = (double)b2f[n * 3 + 0];
    l1 = (double)b2f[n * 3 + 1];
    l2 = (double)b2f[n * 3 + 2];
    #pragma unroll 4
    for (int h = 0; h < 64; ++h) {
        double hv = fma(x1, (double)W1b[h], fma(x0, (double)W1a[h], (double)b1[h]));
        hv = fmax(hv, 0.0);
        l0 = fma(hv, (double)W2[h * 3 + 0], l0);
        l1 = fma(hv, (double)W2[h * 3 + 1], l1);
        l2 = fma(hv, (double)W2[h * 3 + 2], l2);
    }
}

// margin check (r9-proven): tau = 2e-5*(1+0.05*sum|l|), ~40x rms fp32 error.
__device__ __forceinline__ bool tight3(float a, float b, float c) {
    const float m01 = fabsf(a - b), m02 = fabsf(a - c), m12 = fabsf(b - c);
    const float mn = fminf(m01, fminf(m02, m12));
    const float tau = 2e-5f * (1.0f + 0.05f * (fabsf(a) + fabsf(b) + fabsf(c)));
    return mn < tau;
}

// decisions + softmax from (double) logits — identical to passing kernels.
__device__ __forceinline__ void decide(
    double kl0, double kl1, double kl2,
    double wl0, double wl1, double wl2,
    int& kj, int& i0, int& i1, int& i2,
    float& p0, float& p1, float& p2)
{
    kj = 0;
    {
        double m = kl0;
        if (kl1 > m) { m = kl1; kj = 1; }
        if (kl2 > m) { kj = 2; }
    }
    i0 = 0;
    {
        double m = wl0;
        if (wl1 > m) { m = wl1; i0 = 1; }
        if (wl2 > m) { i0 = 2; }
    }
    const int ia = (i0 == 0) ? 1 : 0;
    const int ib = (i0 == 2) ? 1 : 2;
    const double wa = ia ? wl1 : wl0;
    const double wb = (ib == 1) ? wl1 : wl2;
    i1 = (wb > wa) ? ib : ia;
    i2 = (wb > wa) ? ia : ib;

    const double mw = fmax(fmax(wl0, wl1), wl2);
    const float e0 = __expf((float)(wl0 - mw));
    const float e1 = __expf((float)(wl1 - mw));
    const float e2 = __expf((float)(wl2 - mw));
    const float inv = 1.0f / (e0 + e1 + e2);
    p0 = e0 * inv; p1 = e1 * inv; p2 = e2 * inv;
}

__device__ __forceinline__ void epilogue(
    const float acc[12], int i0, int i1, int i2,
    float p0, float p1, float p2, float r[15])
{
    r[0]  = p0; r[5] = p1; r[10] = p2;
    r[1]  = sel3f(i0, acc[0], acc[4], acc[8]);
    r[2]  = sel3f(i0, acc[1], acc[5], acc[9]);
    r[3]  = __expf(sel3f(i0, acc[2], acc[6], acc[10]));
    r[4]  = __expf(sel3f(i0, acc[3], acc[7], acc[11]));
    r[6]  = sel3f(i1, acc[0], acc[4], acc[8]);
    r[7]  = sel3f(i1, acc[1], acc[5], acc[9]);
    r[8]  = __expf(sel3f(i1, acc[2], acc[6], acc[10]));
    r[9]  = __expf(sel3f(i1, acc[3], acc[7], acc[11]));
    r[11] = sel3f(i2, acc[0], acc[4], acc[8]);
    r[12] = sel3f(i2, acc[1], acc[5], acc[9]);
    r[13] = __expf(sel3f(i2, acc[2], acc[6], acc[10]));
    r[14] = __expf(sel3f(i2, acc[3], acc[7], acc[11]));
}

__device__ __forceinline__ void store_point(
    float* __restrict__ out, int p, const float r[15], int kj)
{
    float* o = out + (size_t)p * 15;
    #pragma unroll
    for (int i = 0; i < 15; ++i) o[i] = r[i];
    out[KJS_OFF + p] = (float)(kj + 1);
    float* mk = out + MASK_OFF + (size_t)p * 3;
    mk[0] = 1.0f;
    mk[1] = (kj >= 1) ? 1.0f : 0.0f;
    mk[2] = (kj >= 2) ? 1.0f : 0.0f;
}

// --------------------------------------------------------------------------
// CU-sized blocks: 255 blocks x 1024 threads (16 waves) -> ~1 block/CU.
// n = bid/15 (adjacent bids share n, in case K$ is shared across CU pairs):
// per-CU scalar weight working set = ONE n = 10.75 KB fp32 -> fits the
// 16 KB scalar cache -> s_load stream becomes cache-hits (the 44-49%
// VALUBusy ceiling in r0-r9 was every CU hosting 9-18 distinct n streams
// = 100-190 KB thrash). 1 pt/lane loop over the block's b-chunk; no LDS,
// no barriers; direct stores (r0-proven). Math sequences byte-identical
// to r9 -> bit-identical outputs.
// --------------------------------------------------------------------------
template<bool USE_WS>
__global__ __launch_bounds__(1024, 4) void mdn_fused(
    const float* __restrict__ pred_pts,
    const float* __restrict__ kW1, const float* __restrict__ kb1,
    const float* __restrict__ kW2, const float* __restrict__ kb2,
    const float* __restrict__ wW1, const float* __restrict__ wb1,
    const float* __restrict__ wW2, const float* __restrict__ wb2,
    const float* __restrict__ bW1, const float* __restrict__ bb1,
    const float* __restrict__ bW2, const float* __restrict__ bb2,
    float* __restrict__ out,
    const double* __restrict__ dws)
{
    const int tid   = threadIdx.x;
    const int bid   = blockIdx.x;          // 0..254
    const int n     = bid / NCHUNK;        // 0..16, uniform per block
    const int chunk = bid - n * NCHUNK;    // 0..14
    const int base  = chunk * CHUNKB;
    const int bend  = min(base + CHUNKB, NBATCH);

    for (int b = base + tid; b < bend; b += 1024) {
        const int p = b * NJOINT + n;
        const float2 xv = *reinterpret_cast<const float2*>(pred_pts + 2 * p);
        const float x0 = xv.x, x1 = xv.y;

        // ---- k & w MLPs in fp32 (K$-resident s_load stream) ----
        float kl0f, kl1f, kl2f, wl0f, wl1f, wl2f;
        mlp32_1(kW1, kb1, kW2, kb2, n, x0, x1, kl0f, kl1f, kl2f);
        mlp32_1(wW1, wb1, wW2, wb2, n, x0, x1, wl0f, wl1f, wl2f);

        const bool fl = tight3(kl0f, kl1f, kl2f) || tight3(wl0f, wl1f, wl2f);

        double kl0 = kl0f, kl1 = kl1f, kl2 = kl2f;
        double wl0 = wl0f, wl1 = wl1f, wl2 = wl2f;

        if (__any(fl)) {               // rare: exact fp64 redo for flagged pts
            if constexpr (USE_WS) {
                const double* Wn = dws + (size_t)n * WN_STRIDE;
                if (fl) {
                    mlp64_ws_1(Wn,       (double)x0, (double)x1, kl0, kl1, kl2);
                    mlp64_ws_1(Wn + 387, (double)x0, (double)x1, wl0, wl1, wl2);
                }
            } else {
                if (fl) {
                    mlp64_cvt_1(kW1, kb1, kW2, kb2, n, (double)x0, (double)x1, kl0, kl1, kl2);
                    mlp64_cvt_1(wW1, wb1, wW2, wb2, n, (double)x0, (double)x1, wl0, wl1, wl2);
                }
            }
        }

        int kj, i0, i1, i2;
        float p0, p1, p2;
        decide(kl0, kl1, kl2, wl0, wl1, wl2, kj, i0, i1, i2, p0, p1, p2);

        // ---- bMLP (fp32): 2 -> 128 -> 12 (r9-identical per-point order) ----
        float acc[12];
        {
            const float* W1a = bW1 + n * 256;
            const float* W1b = W1a + 128;
            const float* b1  = bb1 + n * 128;
            const float* W2  = bW2 + n * 1536;
            const float* b2  = bb2 + n * 12;
            #pragma unroll
            for (int j = 0; j < 12; ++j) acc[j] = b2[j];
            #pragma unroll 4
            for (int h = 0; h < 128; ++h) {
                const float wa = W1a[h], wb = W1b[h], bb = b1[h];
                float hv = fmaxf(fmaf(x1, wb, fmaf(x0, wa, bb)), 0.0f);
                #pragma unroll
                for (int j = 0; j < 12; ++j)
                    acc[j] = fmaf(hv, W2[h * 12 + j], acc[j]);
            }
        }

        float r[15];
        epilogue(acc, i0, i1, i2, p0, p1, p2, r);
        store_point(out, p, r, kj);
    }
}

extern "C" void kernel_launch(void* const* d_in, const int* in_sizes, int n_in,
                              void* d_out, int out_size, void* d_ws, size_t ws_size,
                              hipStream_t stream) {
    (void)in_sizes; (void)n_in; (void)out_size;
    const bool use_ws = (d_ws != nullptr) && (ws_size >= (size_t)WS_DOUBLES * sizeof(double));
    dim3 grid(NJOINT * NCHUNK);        // 255 blocks, ~1 per CU
    if (use_ws) {
        cvt_weights_f64<<<NJOINT, 256, 0, stream>>>(
            (const float*)d_in[1], (const float*)d_in[2],
            (const float*)d_in[3], (const float*)d_in[4],
            (const float*)d_in[5], (const float*)d_in[6],
            (const float*)d_in[7], (const float*)d_in[8],
            (double*)d_ws);
        mdn_fused<true><<<grid, 1024, 0, stream>>>(
            (const float*)d_in[0],
            (const float*)d_in[1], (const float*)d_in[2],
            (const float*)d_in[3], (const float*)d_in[4],
            (const float*)d_in[5], (const float*)d_in[6],
            (const float*)d_in[7], (const float*)d_in[8],
            (const float*)d_in[9], (const float*)d_in[10],
            (const float*)d_in[11], (const float*)d_in[12],
            (float*)d_out, (const double*)d_ws);
    } else {
        mdn_fused<false><<<grid, 1024, 0, stream>>>(
            (const float*)d_in[0],
            (const float*)d_in[1], (const float*)d_in[2],
            (const float*)d_in[3], (const float*)d_in[4],
            (const float*)d_in[5], (const float*)d_in[6],
            (const float*)d_in[7], (const float*)d_in[8],
            (const float*)d_in[9], (const float*)d_in[10],
            (const float*)d_in[11], (const float*)d_in[12],
            (float*)d_out, nullptr);
    }
}

// Round 15
// 158.190 us; speedup vs baseline: 1.0541x; 1.0541x over previous
//
#include <hip/hip_runtime.h>
#include <cmath>

// Problem constants: B=32768, N=17, D=2, K=3, H=64
#define NBATCH 32768
#define NJOINT 17
#define OUT0_ELEMS (NBATCH * NJOINT * 15)          // out[B,N,3,5]
#define KJS_OFF    OUT0_ELEMS                      // k_js[B,N]
#define MASK_OFF   (KJS_OFF + NBATCH * NJOINT)     // mask[B,N,3]

#define WN_STRIDE 774
#define WS_DOUBLES (NJOINT * WN_STRIDE)

__device__ __forceinline__ float sel3f(int i, float a, float b, float c) {
    return (i == 0) ? a : ((i == 1) ? b : c);
}

// --------------------------------------------------------------------------
// Prelude: fp64 copies of k/w weights (escape path only).
// --------------------------------------------------------------------------
__global__ void cvt_weights_f64(
    const float* __restrict__ kW1, const float* __restrict__ kb1,
    const float* __restrict__ kW2, const float* __restrict__ kb2,
    const float* __restrict__ wW1, const float* __restrict__ wb1,
    const float* __restrict__ wW2, const float* __restrict__ wb2,
    double* __restrict__ dws)
{
    const int n = blockIdx.x;
    double* o = dws + (size_t)n * WN_STRIDE;
    for (int i = threadIdx.x; i < WN_STRIDE; i += blockDim.x) {
        int j = i;
        const float* W1 = kW1; const float* b1 = kb1;
        const float* W2 = kW2; const float* b2 = kb2;
        if (j >= 387) { j -= 387; W1 = wW1; b1 = wb1; W2 = wW2; b2 = wb2; }
        float v;
        if (j < 128)      v = W1[n * 128 + j];
        else if (j < 192) v = b1[n * 64 + (j - 128)];
        else if (j < 384) v = W2[n * 192 + (j - 192)];
        else              v = b2[n * 3 + (j - 384)];
        o[i] = (double)v;
    }
}

// --------------------------------------------------------------------------
// fp32 MLP (2 -> 64 -> 3) for FOUR points sharing one s_load weight stream.
// Per-point fma sequence identical to r9's (each point's chain is the same
// ops in the same order; only MORE points share each fetched weight).
// 4x compute per SMEM-latency exposure -> per-wave duty model ~36% (r4
// measured 2pts = 22%, 1pt = 12%).
// --------------------------------------------------------------------------
__device__ __forceinline__ void mlp32_4(
    const float* __restrict__ W1, const float* __restrict__ b1f,
    const float* __restrict__ W2f, const float* __restrict__ b2f, int n,
    const float x0[4], const float x1[4],
    float l0[4], float l1[4], float l2[4])
{
    const float* W1a = W1 + n * 128;
    const float* W1b = W1a + 64;
    const float* b1  = b1f + n * 64;
    const float* W2  = W2f + n * 192;
    const float t0 = b2f[n * 3 + 0], t1 = b2f[n * 3 + 1], t2 = b2f[n * 3 + 2];
    #pragma unroll
    for (int i = 0; i < 4; ++i) { l0[i] = t0; l1[i] = t1; l2[i] = t2; }
    #pragma unroll 4
    for (int h = 0; h < 64; ++h) {
        const float wa = W1a[h], wb = W1b[h], bb = b1[h];
        const float w0 = W2[h * 3 + 0], w1 = W2[h * 3 + 1], w2 = W2[h * 3 + 2];
        #pragma unroll
        for (int i = 0; i < 4; ++i) {
            const float hv = fmaxf(fmaf(x1[i], wb, fmaf(x0[i], wa, bb)), 0.0f);
            l0[i] = fmaf(hv, w0, l0[i]);
            l1[i] = fmaf(hv, w1, l1[i]);
            l2[i] = fmaf(hv, w2, l2[i]);
        }
    }
}

// --------------------------------------------------------------------------
// fp64 escape: EXACT sequence of the proven passing kernels.
// --------------------------------------------------------------------------
__device__ __forceinline__ void mlp64_ws_1(
    const double* __restrict__ gws, double x0, double x1,
    double& l0, double& l1, double& l2)
{
    const double* W1a = gws;
    const double* W1b = gws + 64;
    const double* b1  = gws + 128;
    const double* W2  = gws + 192;
    l0 = gws[384]; l1 = gws[385]; l2 = gws[386];
    #pragma unroll 4
    for (int h = 0; h < 64; ++h) {
        double hv = fmax(fma(x1, W1b[h], fma(x0, W1a[h], b1[h])), 0.0);
        l0 = fma(hv, W2[h * 3 + 0], l0);
        l1 = fma(hv, W2[h * 3 + 1], l1);
        l2 = fma(hv, W2[h * 3 + 2], l2);
    }
}

__device__ __forceinline__ void mlp64_cvt_1(
    const float* __restrict__ W1, const float* __restrict__ b1f,
    const float* __restrict__ W2f, const float* __restrict__ b2f, int n,
    double x0, double x1, double& l0, double& l1, double& l2)
{
    const float* W1a = W1 + n * 128;
    const float* W1b = W1a + 64;
    const float* b1  = b1f + n * 64;
    const float* W2  = W2f + n * 192;
    l0 = (double)b2f[n * 3 + 0];
    l1 = (double)b2f[n * 3 + 1];
    l2 = (double)b2f[n * 3 + 2];
    #pragma unroll 4
    for (int h = 0; h < 64; ++h) {
        double hv = fma(x1, (double)W1b[h], fma(x0, (double)W1a[h], (double)b1[h]));
        hv = fmax(hv, 0.0);
        l0 = fma(hv, (double)W2[h * 3 + 0], l0);
        l1 = fma(hv, (double)W2[h * 3 + 1], l1);
        l2 = fma(hv, (double)W2[h * 3 + 2], l2);
    }
}

// margin check (r9-proven): ~3% wave escape rate at 2 pts; ~6% at 4 pts.
__device__ __forceinline__ bool tight3(float a, float b, float c) {
    const float m01 = fabsf(a - b), m02 = fabsf(a - c), m12 = fabsf(b - c);
    const float mn = fminf(m01, fminf(m02, m12));
    const float tau = 2e-5f * (1.0f + 0.05f * (fabsf(a) + fabsf(b) + fabsf(c)));
    return mn < tau;
}

// decisions + softmax from (double) logits — identical to passing kernels.
__device__ __forceinline__ void decide(
    double kl0, double kl1, double kl2,
    double wl0, double wl1, double wl2,
    int& kj, int& i0, int& i1, int& i2,
    float& p0, float& p1, float& p2)
{
    kj = 0;
    {
        double m = kl0;
        if (kl1 > m) { m = kl1; kj = 1; }
        if (kl2 > m) { kj = 2; }
    }
    i0 = 0;
    {
        double m = wl0;
        if (wl1 > m) { m = wl1; i0 = 1; }
        if (wl2 > m) { i0 = 2; }
    }
    const int ia = (i0 == 0) ? 1 : 0;
    const int ib = (i0 == 2) ? 1 : 2;
    const double wa = ia ? wl1 : wl0;
    const double wb = (ib == 1) ? wl1 : wl2;
    i1 = (wb > wa) ? ib : ia;
    i2 = (wb > wa) ? ia : ib;

    const double mw = fmax(fmax(wl0, wl1), wl2);
    const float e0 = __expf((float)(wl0 - mw));
    const float e1 = __expf((float)(wl1 - mw));
    const float e2 = __expf((float)(wl2 - mw));
    const float inv = 1.0f / (e0 + e1 + e2);
    p0 = e0 * inv; p1 = e1 * inv; p2 = e2 * inv;
}

__device__ __forceinline__ void epilogue(
    const float acc[12], int i0, int i1, int i2,
    float p0, float p1, float p2, float r[15])
{
    r[0]  = p0; r[5] = p1; r[10] = p2;
    r[1]  = sel3f(i0, acc[0], acc[4], acc[8]);
    r[2]  = sel3f(i0, acc[1], acc[5], acc[9]);
    r[3]  = __expf(sel3f(i0, acc[2], acc[6], acc[10]));
    r[4]  = __expf(sel3f(i0, acc[3], acc[7], acc[11]));
    r[6]  = sel3f(i1, acc[0], acc[4], acc[8]);
    r[7]  = sel3f(i1, acc[1], acc[5], acc[9]);
    r[8]  = __expf(sel3f(i1, acc[2], acc[6], acc[10]));
    r[9]  = __expf(sel3f(i1, acc[3], acc[7], acc[11]));
    r[11] = sel3f(i2, acc[0], acc[4], acc[8]);
    r[12] = sel3f(i2, acc[1], acc[5], acc[9]);
    r[13] = __expf(sel3f(i2, acc[2], acc[6], acc[10]));
    r[14] = __expf(sel3f(i2, acc[3], acc[7], acc[11]));
}

__device__ __forceinline__ void store_point(
    float* __restrict__ out, int p, const float r[15], int kj)
{
    float* o = out + (size_t)p * 15;
    #pragma unroll
    for (int i = 0; i < 15; ++i) o[i] = r[i];
    out[KJS_OFF + p] = (float)(kj + 1);
    float* mk = out + MASK_OFF + (size_t)p * 3;
    mk[0] = 1.0f;
    mk[1] = (kj >= 1) ? 1.0f : 0.0f;
    mk[2] = (kj >= 2) ? 1.0f : 0.0f;
}

// --------------------------------------------------------------------------
// Block = 2 waves (128 threads) = 2 n x 256 b tile, FOUR points per lane.
// Wave w -> n = 2*by + w; lane handles b = bx*256 + lane + {0,64,128,192}.
// Grid (128, 9) = 1152 blocks -> 4.5 blocks/CU (~2.25 waves/SIMD, r9-level
// supply) at r4-proven amortization x2. LDS stays 17408B by staging/writing
// the tile in two 128-b halves (3 barriers).
// --------------------------------------------------------------------------
template<bool USE_WS>
__global__ __launch_bounds__(128, 2) void mdn_fused(
    const float* __restrict__ pred_pts,
    const float* __restrict__ kW1, const float* __restrict__ kb1,
    const float* __restrict__ kW2, const float* __restrict__ kb2,
    const float* __restrict__ wW1, const float* __restrict__ wb1,
    const float* __restrict__ wW2, const float* __restrict__ wb2,
    const float* __restrict__ bW1, const float* __restrict__ bb1,
    const float* __restrict__ bW2, const float* __restrict__ bb2,
    float* __restrict__ out,
    const double* __restrict__ dws)
{
    const int l    = threadIdx.x;
    const int w    = l >> 6;           // wave id 0..1
    const int lane = l & 63;
    const int bx   = blockIdx.x;       // 0..127
    const int by   = blockIdx.y;       // 0..8
    const int n0   = by * 2;

    if (by == 8 && w == 1) return;     // before any barrier
    int n = n0 + w;                    // by==8: w==0 -> n=16
    n = __builtin_amdgcn_readfirstlane(n);

    int b[4], p[4];
    float x0[4], x1[4];
    #pragma unroll
    for (int i = 0; i < 4; ++i) {
        b[i] = bx * 256 + i * 64 + lane;
        p[i] = b[i] * NJOINT + n;
        const float2 xv = *reinterpret_cast<const float2*>(pred_pts + 2 * p[i]);
        x0[i] = xv.x; x1[i] = xv.y;
    }

    // ---- k & w MLPs in fp32 (one s_load stream, 4 pts) ----
    float kl0f[4], kl1f[4], kl2f[4], wl0f[4], wl1f[4], wl2f[4];
    mlp32_4(kW1, kb1, kW2, kb2, n, x0, x1, kl0f, kl1f, kl2f);
    mlp32_4(wW1, wb1, wW2, wb2, n, x0, x1, wl0f, wl1f, wl2f);

    bool fl[4];
    bool anyf = false;
    #pragma unroll
    for (int i = 0; i < 4; ++i) {
        fl[i] = tight3(kl0f[i], kl1f[i], kl2f[i]) || tight3(wl0f[i], wl1f[i], wl2f[i]);
        anyf = anyf || fl[i];
    }

    double kl0[4], kl1[4], kl2[4], wl0[4], wl1[4], wl2[4];
    #pragma unroll
    for (int i = 0; i < 4; ++i) {
        kl0[i] = kl0f[i]; kl1[i] = kl1f[i]; kl2[i] = kl2f[i];
        wl0[i] = wl0f[i]; wl1[i] = wl1f[i]; wl2[i] = wl2f[i];
    }

    if (__any(anyf)) {                 // rare: exact fp64 redo for flagged pts
        #pragma unroll
        for (int i = 0; i < 4; ++i) {
            if (fl[i]) {
                if constexpr (USE_WS) {
                    const double* Wn = dws + (size_t)n * WN_STRIDE;
                    mlp64_ws_1(Wn,       (double)x0[i], (double)x1[i], kl0[i], kl1[i], kl2[i]);
                    mlp64_ws_1(Wn + 387, (double)x0[i], (double)x1[i], wl0[i], wl1[i], wl2[i]);
                } else {
                    mlp64_cvt_1(kW1, kb1, kW2, kb2, n, (double)x0[i], (double)x1[i], kl0[i], kl1[i], kl2[i]);
                    mlp64_cvt_1(wW1, wb1, wW2, wb2, n, (double)x0[i], (double)x1[i], wl0[i], wl1[i], wl2[i]);
                }
            }
        }
    }

    int kj[4], i0[4], i1[4], i2[4];
    float p0[4], p1[4], p2[4];
    #pragma unroll
    for (int i = 0; i < 4; ++i)
        decide(kl0[i], kl1[i], kl2[i], wl0[i], wl1[i], wl2[i],
               kj[i], i0[i], i1[i], i2[i], p0[i], p1[i], p2[i]);

    // ---- bMLP (fp32): 2 -> 128 -> 12, one s_load stream, 4 pts ----
    float acc[4][12];
    {
        const float* W1a = bW1 + n * 256;
        const float* W1b = W1a + 128;
        const float* b1  = bb1 + n * 128;
        const float* W2  = bW2 + n * 1536;
        const float* b2  = bb2 + n * 12;
        #pragma unroll
        for (int j = 0; j < 12; ++j) {
            const float t = b2[j];
            #pragma unroll
            for (int i = 0; i < 4; ++i) acc[i][j] = t;
        }
        #pragma unroll 2
        for (int h = 0; h < 128; ++h) {
            const float wa = W1a[h], wb = W1b[h], bb = b1[h];
            float hv[4];
            #pragma unroll
            for (int i = 0; i < 4; ++i)
                hv[i] = fmaxf(fmaf(x1[i], wb, fmaf(x0[i], wa, bb)), 0.0f);
            #pragma unroll
            for (int j = 0; j < 12; ++j) {
                const float wv = W2[h * 12 + j];
                #pragma unroll
                for (int i = 0; i < 4; ++i)
                    acc[i][j] = fmaf(hv[i], wv, acc[i][j]);
            }
        }
    }

    float r0v[15], r1v[15], r2v[15], r3v[15];
    epilogue(acc[0], i0[0], i1[0], i2[0], p0[0], p1[0], p2[0], r0v);
    epilogue(acc[1], i0[1], i1[1], i2[1], p0[1], p1[1], p2[1], r1v);
    epilogue(acc[2], i0[2], i1[2], i2[2], p0[2], p1[2], p2[2], r2v);
    epilogue(acc[3], i0[3], i1[3], i2[3], p0[3], p1[3], p2[3], r3v);

    if (by == 8) {
        // n==16 remainder: direct stores (wave 0 only), no barriers.
        store_point(out, p[0], r0v, kj[0]);
        store_point(out, p[1], r1v, kj[1]);
        store_point(out, p[2], r2v, kj[2]);
        store_point(out, p[3], r3v, kj[3]);
        return;
    }

    // ---- two-half LDS staging + coalesced write-back (17408B LDS) ----
    __shared__ float s_out[256 * 17];

    #pragma unroll
    for (int half = 0; half < 2; ++half) {
        // stage: points {2*half, 2*half+1} -> local slots (w*128+lane), (+64)
        {
            float* soA = s_out + (w * 128 + lane) * 17;
            float* soB = soA + 64 * 17;
            const float* rA = (half == 0) ? r0v : r2v;
            const float* rB = (half == 0) ? r1v : r3v;
            #pragma unroll
            for (int j = 0; j < 15; ++j) { soA[j] = rA[j]; soB[j] = rB[j]; }
            soA[15] = (float)(kj[2 * half] + 1);
            soB[15] = (float)(kj[2 * half + 1] + 1);
        }
        __syncthreads();

        // write-back this half's 128 b's: contiguous 120B-per-b runs
        if (l < 120) {
            const int c_off = l / 30;              // 0..3
            const int jj    = l - c_off * 30;      // 0..29
            const int nl    = jj / 15;             // 0..1
            const int j     = jj - nl * 15;        // 0..14
            const int lbase = (nl * 128 + c_off) * 17 + j;
            size_t g = (size_t)((bx * 256 + half * 128 + c_off) * NJOINT + n0) * 15 + jj;
            #pragma unroll
            for (int rr = 0; rr < 32; ++rr) {
                out[g] = s_out[lbase + 68 * rr];   // b_local += 4 -> +4*17 dw
                g += 1020;                          // 4 * 17 * 15 dwords
            }
        }
        // k_js + mask for this half, per-b contiguous pairs
        #pragma unroll
        for (int it = 0; it < 2; ++it) {
            const int q   = it * 128 + l;          // 0..255
            const int bl  = q >> 1;                // 0..127
            const int nlr = q & 1;                 // 0..1
            const float kjf = s_out[(nlr * 128 + bl) * 17 + 15];
            const int pg = (bx * 256 + half * 128 + bl) * NJOINT + n0 + nlr;
            out[KJS_OFF + pg] = kjf;
            float* mk = out + MASK_OFF + (size_t)pg * 3;
            mk[0] = 1.0f;
            mk[1] = (kjf >= 1.5f) ? 1.0f : 0.0f;
            mk[2] = (kjf >= 2.5f) ? 1.0f : 0.0f;
        }
        if (half == 0) __syncthreads();            // reads done before restage
    }
}

extern "C" void kernel_launch(void* const* d_in, const int* in_sizes, int n_in,
                              void* d_out, int out_size, void* d_ws, size_t ws_size,
                              hipStream_t stream) {
    (void)in_sizes; (void)n_in; (void)out_size;
    const bool use_ws = (d_ws != nullptr) && (ws_size >= (size_t)WS_DOUBLES * sizeof(double));
    dim3 grid(NBATCH / 256, 9);        // 1152 blocks
    if (use_ws) {
        cvt_weights_f64<<<NJOINT, 256, 0, stream>>>(
            (const float*)d_in[1], (const float*)d_in[2],
            (const float*)d_in[3], (const float*)d_in[4],
            (const float*)d_in[5], (const float*)d_in[6],
            (const float*)d_in[7], (const float*)d_in[8],
            (double*)d_ws);
        mdn_fused<true><<<grid, 128, 0, stream>>>(
            (const float*)d_in[0],
            (const float*)d_in[1], (const float*)d_in[2],
            (const float*)d_in[3], (const float*)d_in[4],
            (const float*)d_in[5], (const float*)d_in[6],
            (const float*)d_in[7], (const float*)d_in[8],
            (const float*)d_in[9], (const float*)d_in[10],
            (const float*)d_in[11], (const float*)d_in[12],
            (float*)d_out, (const double*)d_ws);
    } else {
        mdn_fused<false><<<grid, 128, 0, stream>>>(
            (const float*)d_in[0],
            (const float*)d_in[1], (const float*)d_in[2],
            (const float*)d_in[3], (const float*)d_in[4],
            (const float*)d_in[5], (const float*)d_in[6],
            (const float*)d_in[7], (const float*)d_in[8],
            (const float*)d_in[9], (const float*)d_in[10],
            (const float*)d_in[11], (const float*)d_in[12],
            (float*)d_out, nullptr);
    }
}